// Round 9
// baseline (145.665 us; speedup 1.0000x reference)
//
#include <hip/hip_runtime.h>

#define NROWS 4096
#define NCOLS 4096
#define TAU 0.95f
#define MARGIN 1.0f
#define INV_TAU (1.0f / TAU)
#define LN2F 0.69314718056f

// R9 (resubmit; previous round died on container-acquire, kernel never ran):
// decisive occupancy test. R7 per-thread shape (8 nt loads, packed scan)
// but 512-thread blocks = 2 rows/block, 4 waves/row, __launch_bounds__(512,8)
// => <=64 VGPR => 4 wg/CU = 32 waves/CU guaranteed (vs R7's reported ~55%).
// Read-concurrency model: rate/CU = lines_in_flight*128B/latency; every
// read-path on this timeline caps at 3.0-3.4 TB/s while the write-only fill
// does 6.6 (no return slots). R8's depth-doubling was confounded (VGPR
// halved waves). This doubles waves at constant per-wave depth. If null:
// per-CU read pool saturated => 131MB/3.4TB/s = 38.5us is the roofline.
typedef int v4i __attribute__((ext_vector_type(4)));
typedef float v4f __attribute__((ext_vector_type(4)));

__global__ __launch_bounds__(512, 8) void attncut_kernel(
    const float* __restrict__ cut_y, const int* __restrict__ cut_label,
    float* __restrict__ partials) {
  const int t = threadIdx.x;   // 0..511
  const int g = t >> 8;        // row-group 0/1 (waves 0-3 / 4-7)
  const int tg = t & 255;      // thread index within the row-group
  const int lane = t & 63;
  const int wid = t >> 6;      // 0..7 (block-wide wave id)
  const int gwid = wid & 3;    // wave id within the row-group
  const int row = (blockIdx.x << 1) | g;

  const v4i* lab4 = (const v4i*)(cut_label + (size_t)row * NCOLS);
  const v4f* yy4 = (const v4f*)(cut_y + (size_t)row * NCOLS);

  // 8 lane-contiguous 16B nt loads (L1-bypass), all issued up-front.
  const v4i L0 = __builtin_nontemporal_load(lab4 + tg);
  const v4i L1 = __builtin_nontemporal_load(lab4 + tg + 256);
  const v4i L2 = __builtin_nontemporal_load(lab4 + tg + 512);
  const v4i L3 = __builtin_nontemporal_load(lab4 + tg + 768);
  const v4f Y0 = __builtin_nontemporal_load(yy4 + tg);
  const v4f Y1 = __builtin_nontemporal_load(yy4 + tg + 256);
  const v4f Y2 = __builtin_nontemporal_load(yy4 + tg + 512);
  const v4f Y3 = __builtin_nontemporal_load(yy4 + tg + 768);

  // Per-quarter label sums (each <= 4), packed into 16-bit fields.
  const int s0 = L0.x + L0.y + L0.z + L0.w;
  const int s1 = L1.x + L1.y + L1.z + L1.w;
  const int s2 = L2.x + L2.y + L2.z + L2.w;
  const int s3 = L3.x + L3.y + L3.z + L3.w;

  unsigned int pa = (unsigned int)s0 | ((unsigned int)s1 << 16);
  unsigned int pb = (unsigned int)s2 | ((unsigned int)s3 << 16);

  unsigned int xa = pa, xb = pb;  // wave-inclusive scan
#pragma unroll
  for (int off = 1; off < 64; off <<= 1) {
    const unsigned int va = __shfl_up(xa, off, 64);
    const unsigned int vb = __shfl_up(xb, off, 64);
    if (lane >= off) {
      xa += va;
      xb += vb;
    }
  }
  __shared__ unsigned int wsA[8], wsB[8];
  if (lane == 63) {
    wsA[wid] = xa;
    wsB[wid] = xb;
  }
  __syncthreads();
  const int gbase = g << 2;
  unsigned int prevA = 0, prevB = 0;
#pragma unroll
  for (int w = 0; w < 4; ++w)
    if (w < gwid) {
      prevA += wsA[gbase + w];
      prevB += wsB[gbase + w];
    }
  const unsigned int totA =
      wsA[gbase] + wsA[gbase + 1] + wsA[gbase + 2] + wsA[gbase + 3];
  const unsigned int totB =
      wsB[gbase] + wsB[gbase + 1] + wsB[gbase + 2] + wsB[gbase + 3];

  const unsigned int exA = prevA + xa - pa;
  const unsigned int exB = prevB + xb - pb;

  const int q0 = (int)(totA & 0xffffu), q1 = (int)(totA >> 16);
  const int q2 = (int)(totB & 0xffffu), q3 = (int)(totB >> 16);
  const float Tf = (float)(q0 + q1 + q2 + q3);

  int c0 = (int)(exA & 0xffffu);
  int c1 = q0 + (int)(exA >> 16);
  int c2 = q0 + q1 + (int)(exB & 0xffffu);
  int c3 = q0 + q1 + q2 + (int)(exB >> 16);

  float na = 0.f;  // sum exp(r/tau)
  float l2 = 0.f;  // sum log2(y) (grouped as log2 of 4-products)

#define QSTEP(cv, LV, YV, EBASE)                                              \
  {                                                                           \
    const float db = (float)(EBASE) + Tf;                                     \
    cv += LV.x;                                                               \
    {                                                                         \
      float r = (cv > 0) ? __fdividef(2.0f * (float)cv, db + 1.0f) : 0.f;     \
      na += __expf(r * INV_TAU);                                              \
    }                                                                         \
    cv += LV.y;                                                               \
    {                                                                         \
      float r = (cv > 0) ? __fdividef(2.0f * (float)cv, db + 2.0f) : 0.f;     \
      na += __expf(r * INV_TAU);                                              \
    }                                                                         \
    cv += LV.z;                                                               \
    {                                                                         \
      float r = (cv > 0) ? __fdividef(2.0f * (float)cv, db + 3.0f) : 0.f;     \
      na += __expf(r * INV_TAU);                                              \
    }                                                                         \
    cv += LV.w;                                                               \
    {                                                                         \
      float r = (cv > 0) ? __fdividef(2.0f * (float)cv, db + 4.0f) : 0.f;     \
      na += __expf(r * INV_TAU);                                              \
    }                                                                         \
    /* y in (1e-4, 1): product of 4 in (1e-16, 1], safe f32 */                \
    l2 += __log2f(YV.x * YV.y * YV.z * YV.w);                                 \
  }

  QSTEP(c0, L0, Y0, 4 * tg)
  QSTEP(c1, L1, Y1, 1024 + 4 * tg)
  QSTEP(c2, L2, Y2, 2048 + 4 * tg)
  QSTEP(c3, L3, Y3, 3072 + 4 * tg)
#undef QSTEP

  // Per-row-group reduction of (na, l2).
#pragma unroll
  for (int off = 32; off > 0; off >>= 1) {
    na += __shfl_down(na, off, 64);
    l2 += __shfl_down(l2, off, 64);
  }
  __shared__ float nred[8], lred[8];
  if (lane == 0) {
    nred[wid] = na;
    lred[wid] = l2;
  }
  __syncthreads();
  if (tg == 0) {  // t==0 (row-group 0) and t==256 (row-group 1)
    const float norm =
        nred[gbase] + nred[gbase + 1] + nred[gbase + 2] + nred[gbase + 3];
    const float lnsum =
        (lred[gbase] + lred[gbase + 1] + lred[gbase + 2] + lred[gbase + 3]) *
        LN2F;
    partials[row] = -lnsum / (norm * (float)NROWS);
  }
}

// Kernel 2 (single block): sum the 4096 per-row partials + rerank hinge loss.
__global__ __launch_bounds__(256) void finish_kernel(
    const float* __restrict__ partials, const float* __restrict__ rerank_y,
    float* __restrict__ out) {
  const int t = threadIdx.x;
  const int lane = t & 63, wid = t >> 6;

  float acc = 0.f;
  const float4* p4 = (const float4*)partials;  // 4096 floats = 1024 float4
#pragma unroll
  for (int i = 0; i < 4; ++i) {
    float4 v = p4[t + 256 * i];
    acc += (v.x + v.y) + (v.z + v.w);
  }

  float racc = 0.f;
  const float4* y4 = (const float4*)rerank_y;  // 8192 floats; float4 = 2 pairs
#pragma unroll
  for (int i = 0; i < 8; ++i) {
    float4 v = y4[t + 256 * i];
    racc += fmaxf(0.f, MARGIN - (v.x - v.y));
    racc += fmaxf(0.f, MARGIN - (v.z - v.w));
  }
  acc += racc * (1.0f / 4096.0f);

#pragma unroll
  for (int off = 32; off > 0; off >>= 1) acc += __shfl_down(acc, off, 64);
  __shared__ float ws[4];
  if (lane == 0) ws[wid] = acc;
  __syncthreads();
  if (t == 0) out[0] = (ws[0] + ws[1]) + (ws[2] + ws[3]);
}

extern "C" void kernel_launch(void* const* d_in, const int* in_sizes, int n_in,
                              void* d_out, int out_size, void* d_ws, size_t ws_size,
                              hipStream_t stream) {
  const float* rerank_y = (const float*)d_in[0];   // (8192, 1) f32
  const float* cut_y = (const float*)d_in[1];      // (4096, 4096, 1) f32
  // d_in[2] = rerank_label, unused by the reference loss
  const int* cut_label = (const int*)d_in[3];      // (4096, 4096) i32
  float* out = (float*)d_out;                      // scalar f32
  float* partials = (float*)d_ws;                  // 4096 f32 (16 KB scratch)

  attncut_kernel<<<NROWS / 2, 512, 0, stream>>>(cut_y, cut_label, partials);
  finish_kernel<<<1, 256, 0, stream>>>(partials, rerank_y, out);
}